// Round 17
// baseline (261.668 us; speedup 1.0000x reference)
//
#include <hip/hip_runtime.h>
#include <math.h>

#define T_SEQ 4096
#define HD 128
#define NH 4
#define DS 512
#define SCALE 0.08838834764831845f
#define NEG9 (-1.0e9f)
#define BN 32
#define NCH 128        // T_SEQ / BN chunks per head
#define NRT 256        // T_SEQ / 16
#define SEG 16         // chunks per j-segment (per block)
#define TOTSEG2 144    // sum over 128-row groups g of ceil((4g+4)/16), per head
#define NVP 32         // V-sum parts per head (128 rows each)
#define ALIVE_MIN (-999999936.0f)

typedef __attribute__((ext_vector_type(8))) _Float16 half8;
typedef __attribute__((ext_vector_type(4))) float floatx4;

__device__ __forceinline__ float sigmoidf_(float x) {
  if (x >= 0.0f) return 1.0f / (1.0f + expf(-x));
  float e = expf(x);
  return e / (1.0f + e);
}

// async global->LDS, 16B per lane: dest = lds_base + lane*16
#define GLDS16(g, l)                                                  \
  __builtin_amdgcn_global_load_lds(                                   \
      (const __attribute__((address_space(1))) void*)(g),             \
      (__attribute__((address_space(3))) void*)(l), 16, 0, 0)

// ---------------- fused prep + sds (unchanged from v7) ----------------
// KVb blob layout (per head h, chunk c, 12288 halves = 24KB, byte-image of LDS stage):
//   [0,4096)     Kh frag-linear ; [4096,8192) Ke ; [8192,12288) V frag-linear
// V rows PERMUTED for swapped-QK PV: lane(quad) elem e holds row
//   perm(quad,e) = quad*4+e (e<4) | 16+quad*4+(e-4) (e>=4)
// bx<512: KV blob | <640: vsum | >=640: sds
__global__ __launch_bounds__(256) void prepsds_kernel(
    const float* __restrict__ Q, const float* __restrict__ K, const float* __restrict__ V,
    _Float16* __restrict__ KVb, float* __restrict__ Vpart, float* __restrict__ sds) {
  const int bx = blockIdx.x, tid = threadIdx.x;
  __shared__ float tile[32][133];
  __shared__ float red[2][128];
  __shared__ float Qs[16][132];
  __shared__ float Ks[16][132];
  if (bx < 512) {  // KV blob for (head, chunk)
    const int hh = bx >> 7, c = bx & 127;
    const int j0 = c * 32;
    const int w = tid >> 6, lane = tid & 63;
    const size_t blob = (size_t)(hh * NCH + c) * 12288;
#pragma unroll
    for (int tt = 0; tt < 2; ++tt) {
      const int t = w + tt * 4;
      const int halfj = t >> 2, dd = t & 3;
      const int q = lane >> 4, jm = lane & 15;
      const float* src =
          &K[(size_t)((hh * T_SEQ) + j0 + halfj * 16 + jm) * HD + dd * 32 + q * 8];
      float4 x0 = *(const float4*)src;
      float4 x1 = *(const float4*)(src + 4);
      float v[8] = {x0.x, x0.y, x0.z, x0.w, x1.x, x1.y, x1.z, x1.w};
      half8 oh, oe;
#pragma unroll
      for (int e = 0; e < 8; ++e) {
        _Float16 hv = (_Float16)v[e];
        oh[e] = hv;
        oe[e] = (_Float16)(v[e] - (float)hv);
      }
      const size_t o = blob + ((size_t)t * 64 + lane) * 8;
      *(half8*)&KVb[o] = oh;
      *(half8*)&KVb[o + 4096] = oe;
    }
    for (int k = 0; k < 4; ++k) {
      int row = (tid >> 5) + k * 8;
      int col = (tid & 31) * 4;
      *(float4*)&tile[row][col] =
          *(const float4*)&V[(size_t)((hh * T_SEQ) + j0 + row) * HD + col];
    }
    __syncthreads();
#pragma unroll
    for (int s2 = 0; s2 < 2; ++s2) {
      const int o8 = tid + s2 * 256;
      const int t2 = o8 >> 6, lane2 = o8 & 63;
      const int qa = lane2 >> 4, dl = lane2 & 15;
      const int col = (t2 >> 1) * 32 + (t2 & 1) * 16 + dl;
      half8 v8;
#pragma unroll
      for (int e = 0; e < 8; ++e) {
        const int row = (e < 4) ? (qa * 4 + e) : (16 + qa * 4 + (e - 4));
        v8[e] = (_Float16)tile[row][col];
      }
      *(half8*)&KVb[blob + 8192 + (size_t)o8 * 8] = v8;
    }
  } else if (bx < 640) {  // V column partial sums
    int b = bx - 512;
    int hh = b >> 5, part = b & 31;
    int d = tid & 127, hlf = tid >> 7;
    const int j0 = part * 128 + hlf;
    float s0 = 0.f, s1 = 0.f;
    for (int j = j0; j < part * 128 + 128; j += 4) {
      s0 += V[(size_t)((hh * T_SEQ) + j) * HD + d];
      s1 += V[(size_t)((hh * T_SEQ) + j + 2) * HD + d];
    }
    red[hlf][d] = s0 + s1;
    __syncthreads();
    if (tid < 128)
      Vpart[(hh * NVP + part) * 128 + tid] = red[0][tid] + red[1][tid];
  } else {  // downsampled scores (bit-identical)
    int b = bx - 640;
    const int bxs = b & 31, bys = (b >> 5) & 31, hh = b >> 10;
    for (int t = tid; t < 512; t += 256) {
      int r = t >> 5, f = (t & 31) * 4;
      *(float4*)&Qs[r][f] = *(const float4*)&Q[((hh * T_SEQ) + (bys * 16 + r) * 8) * HD + f];
      *(float4*)&Ks[r][f] = *(const float4*)&K[((hh * T_SEQ) + (bxs * 16 + r) * 8) * HD + f];
    }
    __syncthreads();
    const int ty = tid >> 4, tx = tid & 15;
    float acc = 0.0f;
    for (int k = 0; k < 32; ++k) {
      float4 a = *(float4*)&Qs[ty][k * 4];
      float4 bq = *(float4*)&Ks[tx][k * 4];
      acc += a.x * bq.x + a.y * bq.y + a.z * bq.z + a.w * bq.w;
    }
    sds[((hh * DS) + bys * 16 + ty) * DS + bxs * 16 + tx] = acc * SCALE;
  }
}

// ---------------- Kernel B: exact 128th-largest + bias max (unchanged) ----------------
__global__ __launch_bounds__(256) void bmaxthr_kernel(const float* __restrict__ sds,
                                                      const float* __restrict__ U,
                                                      float* __restrict__ thrG,
                                                      float* __restrict__ bmax16) {
  const int h = blockIdx.y, rt = blockIdx.x;
  const int tid = threadIdx.x, ww = tid >> 6, lane = tid & 63;
  __shared__ float thrS[2];
  if (ww < 2) {
    const int row = h * DS + rt * 2 + ww;
    unsigned v[8];
    for (int t = 0; t < 8; ++t) {
      float f = sds[(size_t)row * DS + t * 64 + lane];
      unsigned b = __float_as_uint(f);
      v[t] = (b & 0x80000000u) ? ~b : (b | 0x80000000u);
    }
    unsigned prefix = 0u;
    for (int bit = 31; bit >= 0; --bit) {
      unsigned cand = prefix | (1u << bit);
      int c = 0;
      for (int t = 0; t < 8; ++t) c += (v[t] >= cand) ? 1 : 0;
      for (int off = 32; off > 0; off >>= 1) c += __shfl_down(c, off, 64);
      c = __shfl(c, 0, 64);
      if (c >= 128) prefix = cand;
    }
    if (lane == 0) {
      unsigned b = (prefix & 0x80000000u) ? (prefix ^ 0x80000000u) : ~prefix;
      float t = __uint_as_float(b);
      thrS[ww] = t;
      thrG[row] = t;
    }
  }
  __syncthreads();
  const int r = lane >> 2, q = lane & 3;
  const int i = rt * 16 + r;
  float u = U[i];
  u = fminf(fmaxf(u, 0.0f), 1.0f);
  const float us = 1.0f + u;
  const int idl = r >> 3;
  const float bb = us * thrS[idl];
  const float* srow = &sds[((h * DS) + rt * 2 + idl) * DS];
  for (int c = ww; c < NCH; c += 4) {
    float sval = srow[(c << 2) + q];
    float a = us * sval;
    float bias = (1.0f - sigmoidf_((a - bb) * 10.0f)) * NEG9;
    for (int off = 1; off < 64; off <<= 1)
      bias = fmaxf(bias, __shfl_xor(bias, off, 64));
    if (lane == 0) bmax16[((h * NRT) + rt) * NCH + c] = bias;
  }
}

// ---------------- Kernel C v8: 4 waves x 32 rows -- K/V LDS reads shared by 2 tiles ----------------
// DS-b128 stream was the bottleneck (24 reads/wave/chunk, 8x redundant). Now each
// wave owns TWO 16-row tiles: same 24 reads serve double the MFMA work.
__global__ __launch_bounds__(256) void attn128_kernel(
    const float* __restrict__ Qf, const _Float16* __restrict__ KVb,
    const float* __restrict__ U, const float* __restrict__ sds,
    const float* __restrict__ thrG, const float* __restrict__ bmax16,
    float* __restrict__ Pm, float* __restrict__ Pl, _Float16* __restrict__ Po,
    const float* __restrict__ Vpart, float* __restrict__ out) {
  const int h = blockIdx.y;
  const int p = TOTSEG2 - 1 - (int)blockIdx.x;  // heavy segs first
  int s = 0;
#pragma unroll
  for (int t = 1; t <= 7; ++t)
    if (p >= 32 * t - 2 * t * (t - 1)) s = t;
  const int g = 4 * s + (p - (32 * s - 2 * s * (s - 1)));
  const int seg = s;
  const int cmax = 4 * g + 4;
  const int c0 = seg * SEG;
  const int len = min(SEG, cmax - c0);
  const int nsegG = (cmax + 15) >> 4;

  const int tid = threadIdx.x;
  const int w = tid >> 6;         // 0..3
  const int lane = tid & 63;
  const int quad = lane >> 4;
  const int n = lane & 15;

  __shared__ __align__(16) _Float16 Sbuf[2][12288];
  __shared__ unsigned uHot[4], uNN[4];
  __shared__ float VsS[128];

  // two 16-row tiles per wave: rows iw0t[tt] + n ; rt[tt] = g*8 + w*2 + tt
  int iw0t[2], rtt[2], myid[2];
  float usn[2], bbn[2];
#pragma unroll
  for (int tt = 0; tt < 2; ++tt) {
    iw0t[tt] = g * 128 + (w * 2 + tt) * 16;
    rtt[tt] = g * 8 + w * 2 + tt;
    myid[tt] = (iw0t[tt] >> 3) + (n >> 3);
    float u = U[iw0t[tt] + n];
    u = fminf(fmaxf(u, 0.0f), 1.0f);
    usn[tt] = 1.0f + u;
    bbn[tt] = usn[tt] * thrG[h * DS + myid[tt]];
  }

  // Q fragments (MFMA B operand) for both tiles
  half8 qfh[2][4], qfe[2][4];
#pragma unroll
  for (int tt = 0; tt < 2; ++tt) {
    const float* qrow = &Qf[(size_t)((h * T_SEQ) + iw0t[tt] + n) * HD + quad * 8];
#pragma unroll
    for (int d = 0; d < 4; ++d) {
      float4 x0 = *(const float4*)&qrow[d * 32];
      float4 x1 = *(const float4*)&qrow[d * 32 + 4];
      float v[8] = {x0.x, x0.y, x0.z, x0.w, x1.x, x1.y, x1.z, x1.w};
      half8 hh, ee;
#pragma unroll
      for (int t = 0; t < 8; ++t) {
        _Float16 hv = (_Float16)v[t];
        hh[t] = hv;
        ee[t] = (_Float16)(v[t] - (float)hv);
      }
      qfh[tt][d] = hh;
      qfe[tt][d] = ee;
    }
  }
  half8 vones;
#pragma unroll
  for (int e = 0; e < 8; ++e) vones[e] = (_Float16)1.0f;

  floatx4 acc[2][8];
#pragma unroll
  for (int tt = 0; tt < 2; ++tt)
    for (int t = 0; t < 8; ++t) acc[tt][t] = (floatx4){0.f, 0.f, 0.f, 0.f};
  floatx4 accL[2];
  accL[0] = (floatx4){0.f, 0.f, 0.f, 0.f};
  accL[1] = (floatx4){0.f, 0.f, 0.f, 0.f};
  float m_[2] = {-INFINITY, -INFINITY};

  // planning: classify per tile, wave = union
  float bv[2] = {-3.0e38f, -3.0e38f};
  bool hot0 = false, hot1 = false, nul0 = true, nul1 = true;
  if (lane < len) {
    int c = c0 + lane;
#pragma unroll
    for (int tt = 0; tt < 2; ++tt) {
      bool vd = (c < (rtt[tt] >> 1) + 1);
      float b = bmax16[((h * NRT) + rtt[tt]) * NCH + c];
      bv[tt] = b;
      bool ht = vd && b > -124.0f;
      bool nl = (!vd) || b == NEG9;
      if (tt == 0) { hot0 = ht; nul0 = nl; } else { hot1 = ht; nul1 = nl; }
    }
  }
  const float bvalM = fmaxf(bv[0], bv[1]);
  const unsigned bits = (1u << len) - 1u;
  const unsigned myHot = (unsigned)__ballot(lane < len && (hot0 || hot1)) & bits;
  const unsigned myNull = (unsigned)__ballot(lane < len && nul0 && nul1) & bits;
  const unsigned myCold = bits & ~myHot & ~myNull;
  if (lane == 0) { uHot[w] = myHot; uNN[w] = myHot | myCold; }
  __syncthreads();
  unsigned it0 = uHot[0] | uHot[1] | uHot[2] | uHot[3];
  unsigned it1 = (uNN[0] | uNN[1] | uNN[2] | uNN[3]) & ~it0;

  const size_t hcbase = (size_t)(h * NCH);
  // wave w DMAs bytes [w*6144, (w+1)*6144) of the 24KB blob: 6 x (64 lanes x 16B)
#define STAGE(cc, bsel)                                                          \
  {                                                                              \
    const _Float16* gsrc =                                                       \
        KVb + (hcbase + (size_t)(c0 + (cc))) * 12288 + w * 3072 + lane * 8;      \
    _Float16* ldst = &Sbuf[bsel][w * 3072];                                      \
    GLDS16(gsrc, ldst);                                                          \
    GLDS16(gsrc + 512, ldst + 512);                                              \
    GLDS16(gsrc + 1024, ldst + 1024);                                            \
    GLDS16(gsrc + 1536, ldst + 1536);                                            \
    GLDS16(gsrc + 2048, ldst + 2048);                                            \
    GLDS16(gsrc + 2560, ldst + 2560);                                            \
  }

  int curc = -1;
  if (it0) { curc = __builtin_ctz(it0); it0 &= it0 - 1; }
  else if (it1) { curc = __builtin_ctz(it1); it1 &= it1 - 1; }
  int cur = 0;
  if (curc >= 0) STAGE(curc, 0);

  while (curc >= 0) {
    __syncthreads();
    int nxtc = -1;
    if (it0) { nxtc = __builtin_ctz(it0); it0 &= it0 - 1; }
    else if (it1) { nxtc = __builtin_ctz(it1); it1 &= it1 - 1; }
    if (nxtc >= 0) STAGE(nxtc, cur ^ 1);

    bool run = ((myHot | myCold) >> curc) & 1;
    if (run && ((myCold >> curc) & 1)) {
      float bm16 = __shfl(bvalM, curc, 64);
      float mm = fminf(m_[0], m_[1]);
      for (int d = 1; d < 16; d <<= 1) mm = fminf(mm, __shfl_xor(mm, d, 64));
      if (bm16 + 12.0f < mm - 40.0f) run = false;
    }
    if (run) {
      const _Float16* Sb = &Sbuf[cur][0];
      const int c = c0 + curc;
      const int j0 = c * BN;
      const int jj = quad >> 1;

      // per-lane bias: 2 sds scalars + 2 sigmoids per tile (same values as v7)
      float bias1[2], bias2[2];
#pragma unroll
      for (int tt = 0; tt < 2; ++tt) {
        const float sv1 = sds[((h * DS) + myid[tt]) * DS + (c << 2) + jj];
        const float sv2 = sds[((h * DS) + myid[tt]) * DS + (c << 2) + 2 + jj];
        bias1[tt] = (1.0f - sigmoidf_((usn[tt] * sv1 - bbn[tt]) * 10.0f)) * NEG9;
        bias2[tt] = (1.0f - sigmoidf_((usn[tt] * sv2 - bbn[tt]) * 10.0f)) * NEG9;
      }

      // S^T = K @ Q^T, both tiles share each K fragment read
      floatx4 S0[2], S1[2];
      S0[0] = (floatx4){0.f, 0.f, 0.f, 0.f};
      S0[1] = (floatx4){0.f, 0.f, 0.f, 0.f};
      S1[0] = (floatx4){0.f, 0.f, 0.f, 0.f};
      S1[1] = (floatx4){0.f, 0.f, 0.f, 0.f};
#pragma unroll
      for (int d = 0; d < 4; ++d) {
        const half8 k0 = *(const half8*)&Sb[(size_t)(d * 64 + lane) * 8];
        const half8 k1 = *(const half8*)&Sb[(size_t)((4 + d) * 64 + lane) * 8];
        S0[0] = __builtin_amdgcn_mfma_f32_16x16x32_f16(k0, qfh[0][d], S0[0], 0, 0, 0);
        S1[0] = __builtin_amdgcn_mfma_f32_16x16x32_f16(k1, qfh[0][d], S1[0], 0, 0, 0);
        S0[1] = __builtin_amdgcn_mfma_f32_16x16x32_f16(k0, qfh[1][d], S0[1], 0, 0, 0);
        S1[1] = __builtin_amdgcn_mfma_f32_16x16x32_f16(k1, qfh[1][d], S1[1], 0, 0, 0);
        S0[0] = __builtin_amdgcn_mfma_f32_16x16x32_f16(k0, qfe[0][d], S0[0], 0, 0, 0);
        S1[0] = __builtin_amdgcn_mfma_f32_16x16x32_f16(k1, qfe[0][d], S1[0], 0, 0, 0);
        S0[1] = __builtin_amdgcn_mfma_f32_16x16x32_f16(k0, qfe[1][d], S0[1], 0, 0, 0);
        S1[1] = __builtin_amdgcn_mfma_f32_16x16x32_f16(k1, qfe[1][d], S1[1], 0, 0, 0);
      }
#pragma unroll
      for (int d = 0; d < 4; ++d) {
        const half8 e0 = *(const half8*)&Sb[4096 + (size_t)(d * 64 + lane) * 8];
        const half8 e1 = *(const half8*)&Sb[4096 + (size_t)((4 + d) * 64 + lane) * 8];
        S0[0] = __builtin_amdgcn_mfma_f32_16x16x32_f16(e0, qfh[0][d], S0[0], 0, 0, 0);
        S1[0] = __builtin_amdgcn_mfma_f32_16x16x32_f16(e1, qfh[0][d], S1[0], 0, 0, 0);
        S0[1] = __builtin_amdgcn_mfma_f32_16x16x32_f16(e0, qfh[1][d], S0[1], 0, 0, 0);
        S1[1] = __builtin_amdgcn_mfma_f32_16x16x32_f16(e1, qfh[1][d], S1[1], 0, 0, 0);
      }

      // scores + defer-max per tile (wave-uniform branch over both tiles)
      float sc0[2][4], sc1[2][4];
#pragma unroll
      for (int tt = 0; tt < 2; ++tt) {
        const int i = iw0t[tt] + n;
        for (int r = 0; r < 4; ++r) {
          const int jA = j0 + quad * 4 + r;
          sc0[tt][r] = (jA <= i) ? (S0[tt][r] * SCALE + bias1[tt]) : NEG9;
          sc1[tt][r] = (jA + 16 <= i) ? (S1[tt][r] * SCALE + bias2[tt]) : NEG9;
        }
      }
      bool within = true;
#pragma unroll
      for (int tt = 0; tt < 2; ++tt)
        for (int r = 0; r < 4; ++r)
          within = within && (sc0[tt][r] <= m_[tt] + 8.0f) &&
                   (sc1[tt][r] <= m_[tt] + 8.0f);
      _Float16 ph0[2][4], ph1[2][4];
      if (__all(within)) {
#pragma unroll
        for (int tt = 0; tt < 2; ++tt)
          for (int r = 0; r < 4; ++r) {
            ph0[tt][r] = (_Float16)__expf(sc0[tt][r] - m_[tt]);
            ph1[tt][r] = (_Float16)__expf(sc1[tt][r] - m_[tt]);
          }
      } else {
#pragma unroll
        for (int tt = 0; tt < 2; ++tt) {
          float mx = sc0[tt][0];
          for (int r = 1; r < 4; ++r) mx = fmaxf(mx, sc0[tt][r]);
          for (int r = 0; r < 4; ++r) mx = fmaxf(mx, sc1[tt][r]);
          mx = fmaxf(mx, __shfl_xor(mx, 16, 64));
          mx = fmaxf(mx, __shfl_xor(mx, 32, 64));
          const float mnew = fmaxf(m_[tt], mx);
          const float alpha = __expf(m_[tt] - mnew);  // -inf -> 0
          for (int r = 0; r < 4; ++r) {
            ph0[tt][r] = (_Float16)__expf(sc0[tt][r] - mnew);
            ph1[tt][r] = (_Float16)__expf(sc1[tt][r] - mnew);
          }
          m_[tt] = mnew;
          if (__any(alpha != 1.0f)) {
            float aO[4];
#pragma unroll
            for (int r = 0; r < 4; ++r) aO[r] = __shfl(alpha, quad * 4 + r, 64);
            for (int t = 0; t < 8; ++t)
              for (int r = 0; r < 4; ++r) acc[tt][t][r] *= aO[r];
            for (int r = 0; r < 4; ++r) accL[tt][r] *= aO[r];
          }
        }
      }

      half8 pp0, pp1;
#pragma unroll
      for (int r = 0; r < 4; ++r) {
        pp0[r] = ph0[0][r]; pp0[4 + r] = ph1[0][r];
        pp1[r] = ph0[1][r]; pp1[4 + r] = ph1[1][r];
      }

      // PV: each V fragment read once, feeds both tiles
#pragma unroll
      for (int t = 0; t < 8; ++t) {
        const half8 vf = *(const half8*)&Sb[8192 + (size_t)(t * 64 + lane) * 8];
        acc[0][t] = __builtin_amdgcn_mfma_f32_16x16x32_f16(pp0, vf, acc[0][t], 0, 0, 0);
        acc[1][t] = __builtin_amdgcn_mfma_f32_16x16x32_f16(pp1, vf, acc[1][t], 0, 0, 0);
      }
      accL[0] = __builtin_amdgcn_mfma_f32_16x16x32_f16(pp0, vones, accL[0], 0, 0, 0);
      accL[1] = __builtin_amdgcn_mfma_f32_16x16x32_f16(pp1, vones, accL[1], 0, 0, 0);
    }
    cur ^= 1;
    curc = nxtc;
  }

  // per-output-row m for rows quad*4+r of each tile
  float mrow[2][4];
#pragma unroll
  for (int tt = 0; tt < 2; ++tt)
    for (int r = 0; r < 4; ++r) mrow[tt][r] = __shfl(m_[tt], quad * 4 + r, 64);

  if (nsegG == 1) {
    if (tid < 128) {
      float ss = 0.f;
      for (int pt = 0; pt < NVP; ++pt) ss += Vpart[(h * NVP + pt) * 128 + tid];
      VsS[tid] = ss;
    }
    __syncthreads();
#pragma unroll
    for (int tt = 0; tt < 2; ++tt)
      for (int r = 0; r < 4; ++r) {
        const int row = iw0t[tt] + quad * 4 + r;
        const bool dead = (mrow[tt][r] < ALIVE_MIN);
        const float Linv = dead ? 0.0f : 1.0f / accL[tt][r];
#pragma unroll
        for (int t = 0; t < 8; ++t) {
          const int col = t * 16 + n;
          float o = dead ? VsS[col] * 0.000244140625f : acc[tt][t][r] * Linv;
          out[(size_t)((h * T_SEQ) + row) * HD + col] = o;
        }
      }
    return;
  }
  __syncthreads();
  const size_t pbase = (size_t)(h * TOTSEG2 + p);
  if (quad == 0) {
    Pm[pbase * 128 + (w * 2 + 0) * 16 + n] = m_[0];
    Pm[pbase * 128 + (w * 2 + 1) * 16 + n] = m_[1];
  }
  if (n == 0) {
#pragma unroll
    for (int tt = 0; tt < 2; ++tt)
      for (int r = 0; r < 4; ++r)
        Pl[pbase * 128 + (w * 2 + tt) * 16 + quad * 4 + r] = accL[tt][r];
  }
  _Float16* Ob = &Sbuf[0][0];
#pragma unroll
  for (int tt = 0; tt < 2; ++tt)
    for (int t = 0; t < 8; ++t)
      for (int r = 0; r < 4; ++r)
        Ob[(size_t)((w * 2 + tt) * 16 + quad * 4 + r) * 128 + t * 16 + n] =
            (_Float16)acc[tt][t][r];
  __syncthreads();
  {
    const half8* Os = (const half8*)Ob;
    half8* Pod = (half8*)&Po[pbase * 16384];
    for (int idx = tid; idx < 2048; idx += 256) Pod[idx] = Os[idx];
  }
}

// ---------------- Reduce v2: 16-row sub-blocks, vectorized half8 loads (unchanged) ----------------
__global__ __launch_bounds__(256) void reduce128_kernel(const float* __restrict__ Pm,
                                                        const float* __restrict__ Pl,
                                                        const _Float16* __restrict__ Po,
                                                        const float* __restrict__ Vpart,
                                                        float* __restrict__ out) {
  const int bx = blockIdx.x;
  const int g = 4 + (bx >> 3);        // groups 4..31
  const int rb = bx & 7;              // 16-row sub-block
  const int h = blockIdx.y;
  const int ns = (g >> 2) + 1;        // 2..8
  const int tid = threadIdx.x;
  const int lr = tid >> 4;            // 0..15 local row
  const int d0 = (tid & 15) * 8;      // col start
  const int r = rb * 16 + lr;         // row within 128-row group

  float m[8], M = -INFINITY;
  int pp[8];
#pragma unroll
  for (int ss = 0; ss < 8; ++ss) {
    if (ss < ns) {
      pp[ss] = 32 * ss - 2 * ss * (ss - 1) + g - 4 * ss;
      m[ss] = Pm[(size_t)(h * TOTSEG2 + pp[ss]) * 128 + r];
      M = fmaxf(M, m[ss]);
    }
  }
  const bool dead = (M < ALIVE_MIN);
  float es[8], L = 0.f;
#pragma unroll
  for (int ss = 0; ss < 8; ++ss) {
    if (ss < ns) {
      es[ss] = (dead || m[ss] == -INFINITY) ? 0.0f : expf(m[ss] - M);
      L += Pl[(size_t)(h * TOTSEG2 + pp[ss]) * 128 + r] * es[ss];
    }
  }

  float o[8];
#pragma unroll
  for (int e = 0; e < 8; ++e) o[e] = 0.f;
  if (dead) {
    float4 sa = {0.f, 0.f, 0.f, 0.f}, sb = {0.f, 0.f, 0.f, 0.f};
    for (int pt = 0; pt < NVP; ++pt) {
      const float* vp = &Vpart[(h * NVP + pt) * 128 + d0];
      float4 x0 = *(const float4*)vp;
      float4 x1 = *(const float4*)(vp + 4);
      sa.x += x0.x; sa.y += x0.y; sa.z += x0.z; sa.w += x0.w;
      sb.x += x1.x; sb.y += x1.y; sb.z += x1.z; sb.w += x1.w;
    }
    o[0] = sa.x * 0.000244140625f; o[1] = sa.y * 0.000244140625f;
    o[2] = sa.z * 0.000244140625f; o[3] = sa.w * 0.000244140625f;
    o[4] = sb.x * 0.000244140625f; o[5] = sb.y * 0.000244140625f;
    o[6] = sb.z * 0.000244140625f; o[7] = sb.w * 0.000244140625f;
  } else {
    const float Linv = 1.0f / L;
#pragma unroll
    for (int ss = 0; ss < 8; ++ss) {
      if (ss < ns) {
        half8 v = *(const half8*)&Po[(size_t)(h * TOTSEG2 + pp[ss]) * 16384 + r * 128 + d0];
#pragma unroll
        for (int e = 0; e < 8; ++e) o[e] += (float)v[e] * es[ss];
      }
    }
#pragma unroll
    for (int e = 0; e < 8; ++e) o[e] *= Linv;
  }
  float* dst = &out[(size_t)((h * T_SEQ) + g * 128 + r) * HD + d0];
  float4 w0 = {o[0], o[1], o[2], o[3]};
  float4 w1 = {o[4], o[5], o[6], o[7]};
  *(float4*)dst = w0;
  *(float4*)(dst + 4) = w1;
}

extern "C" void kernel_launch(void* const* d_in, const int* in_sizes, int n_in,
                              void* d_out, int out_size, void* d_ws, size_t ws_size,
                              hipStream_t stream) {
  const float* Q = (const float*)d_in[0];
  const float* K = (const float*)d_in[1];
  const float* V = (const float*)d_in[2];
  const float* U = (const float*)d_in[3];
  float* out = (float*)d_out;

  char* wsb = (char*)d_ws;
  float* sds = (float*)wsb;                        // 4 MB
  float* thrG = (float*)(wsb + 4194304);           // 8 KB
  float* bmax16 = (float*)(wsb + 4202496);         // 512 KB
  float* Vpart = (float*)(wsb + 4726784);          // 64 KB
  _Float16* KVb = (_Float16*)(wsb + 4792320);      // 12 MB chunk blobs (Kh|Ke|V)
  float* Pm = (float*)(wsb + 17375232);            // 288 KB
  float* Pl = (float*)(wsb + 17670144);            // 288 KB
  _Float16* Po = (_Float16*)(wsb + 17965056);      // 18.9 MB -> total ~35.2 MB

  prepsds_kernel<<<4736, 256, 0, stream>>>(Q, K, V, KVb, Vpart, sds);
  bmaxthr_kernel<<<dim3(NRT, NH), 256, 0, stream>>>(sds, U, thrG, bmax16);
  attn128_kernel<<<dim3(TOTSEG2, NH), 256, 0, stream>>>(Q, KVb, U, sds, thrG, bmax16,
                                                        Pm, Pl, Po, Vpart, out);
  reduce128_kernel<<<dim3(224, NH), 256, 0, stream>>>(Pm, Pl, Po, Vpart, out);
}

// Round 19
// 218.491 us; speedup vs baseline: 1.1976x; 1.1976x over previous
//
#include <hip/hip_runtime.h>
#include <math.h>

#define T_SEQ 4096
#define HD 128
#define NH 4
#define DS 512
#define SCALE 0.08838834764831845f
#define NEG9 (-1.0e9f)
#define BN 32
#define NCH 128        // T_SEQ / BN chunks per head
#define NRT 256        // T_SEQ / 16
#define SEG 16         // chunks per j-segment (per block)
#define TOTSEG2 144    // sum over 128-row groups g of ceil((4g+4)/16), per head
#define NVP 32         // V-sum parts per head (128 rows each)
#define ALIVE_MIN (-999999936.0f)

typedef __attribute__((ext_vector_type(8))) _Float16 half8;
typedef __attribute__((ext_vector_type(4))) float floatx4;

__device__ __forceinline__ float sigmoidf_(float x) {
  if (x >= 0.0f) return 1.0f / (1.0f + expf(-x));
  float e = expf(x);
  return e / (1.0f + e);
}

// async global->LDS, 16B per lane: dest = lds_base + lane*16
#define GLDS16(g, l)                                                  \
  __builtin_amdgcn_global_load_lds(                                   \
      (const __attribute__((address_space(1))) void*)(g),             \
      (__attribute__((address_space(3))) void*)(l), 16, 0, 0)

// ---------------- fused prep + sds (v7, unchanged) ----------------
// KVb blob layout (per head h, chunk c, 12288 halves = 24KB, byte-image of LDS stage):
//   [0,4096)     Kh frag-linear ; [4096,8192) Ke ; [8192,12288) V frag-linear
// V rows PERMUTED for swapped-QK PV: lane(quad) elem e holds row
//   perm(quad,e) = quad*4+e (e<4) | 16+quad*4+(e-4) (e>=4)
// bx<512: KV blob | <640: vsum | >=640: sds
__global__ __launch_bounds__(256) void prepsds_kernel(
    const float* __restrict__ Q, const float* __restrict__ K, const float* __restrict__ V,
    _Float16* __restrict__ KVb, float* __restrict__ Vpart, float* __restrict__ sds) {
  const int bx = blockIdx.x, tid = threadIdx.x;
  __shared__ float tile[32][133];
  __shared__ float red[2][128];
  __shared__ float Qs[16][132];
  __shared__ float Ks[16][132];
  if (bx < 512) {  // KV blob for (head, chunk)
    const int hh = bx >> 7, c = bx & 127;
    const int j0 = c * 32;
    const int w = tid >> 6, lane = tid & 63;
    const size_t blob = (size_t)(hh * NCH + c) * 12288;
#pragma unroll
    for (int tt = 0; tt < 2; ++tt) {
      const int t = w + tt * 4;
      const int halfj = t >> 2, dd = t & 3;
      const int q = lane >> 4, jm = lane & 15;
      const float* src =
          &K[(size_t)((hh * T_SEQ) + j0 + halfj * 16 + jm) * HD + dd * 32 + q * 8];
      float4 x0 = *(const float4*)src;
      float4 x1 = *(const float4*)(src + 4);
      float v[8] = {x0.x, x0.y, x0.z, x0.w, x1.x, x1.y, x1.z, x1.w};
      half8 oh, oe;
#pragma unroll
      for (int e = 0; e < 8; ++e) {
        _Float16 hv = (_Float16)v[e];
        oh[e] = hv;
        oe[e] = (_Float16)(v[e] - (float)hv);
      }
      const size_t o = blob + ((size_t)t * 64 + lane) * 8;
      *(half8*)&KVb[o] = oh;
      *(half8*)&KVb[o + 4096] = oe;
    }
    for (int k = 0; k < 4; ++k) {
      int row = (tid >> 5) + k * 8;
      int col = (tid & 31) * 4;
      *(float4*)&tile[row][col] =
          *(const float4*)&V[(size_t)((hh * T_SEQ) + j0 + row) * HD + col];
    }
    __syncthreads();
#pragma unroll
    for (int s2 = 0; s2 < 2; ++s2) {
      const int o8 = tid + s2 * 256;
      const int t2 = o8 >> 6, lane2 = o8 & 63;
      const int qa = lane2 >> 4, dl = lane2 & 15;
      const int col = (t2 >> 1) * 32 + (t2 & 1) * 16 + dl;
      half8 v8;
#pragma unroll
      for (int e = 0; e < 8; ++e) {
        const int row = (e < 4) ? (qa * 4 + e) : (16 + qa * 4 + (e - 4));
        v8[e] = (_Float16)tile[row][col];
      }
      *(half8*)&KVb[blob + 8192 + (size_t)o8 * 8] = v8;
    }
  } else if (bx < 640) {  // V column partial sums
    int b = bx - 512;
    int hh = b >> 5, part = b & 31;
    int d = tid & 127, hlf = tid >> 7;
    const int j0 = part * 128 + hlf;
    float s0 = 0.f, s1 = 0.f;
    for (int j = j0; j < part * 128 + 128; j += 4) {
      s0 += V[(size_t)((hh * T_SEQ) + j) * HD + d];
      s1 += V[(size_t)((hh * T_SEQ) + j + 2) * HD + d];
    }
    red[hlf][d] = s0 + s1;
    __syncthreads();
    if (tid < 128)
      Vpart[(hh * NVP + part) * 128 + tid] = red[0][tid] + red[1][tid];
  } else {  // downsampled scores (bit-identical)
    int b = bx - 640;
    const int bxs = b & 31, bys = (b >> 5) & 31, hh = b >> 10;
    for (int t = tid; t < 512; t += 256) {
      int r = t >> 5, f = (t & 31) * 4;
      *(float4*)&Qs[r][f] = *(const float4*)&Q[((hh * T_SEQ) + (bys * 16 + r) * 8) * HD + f];
      *(float4*)&Ks[r][f] = *(const float4*)&K[((hh * T_SEQ) + (bxs * 16 + r) * 8) * HD + f];
    }
    __syncthreads();
    const int ty = tid >> 4, tx = tid & 15;
    float acc = 0.0f;
    for (int k = 0; k < 32; ++k) {
      float4 a = *(float4*)&Qs[ty][k * 4];
      float4 bq = *(float4*)&Ks[tx][k * 4];
      acc += a.x * bq.x + a.y * bq.y + a.z * bq.z + a.w * bq.w;
    }
    sds[((hh * DS) + bys * 16 + ty) * DS + bxs * 16 + tx] = acc * SCALE;
  }
}

// ---------------- Kernel B v2: ballot-count radix select + max-then-sigmoid ----------------
// (a) per-bit count via 8x ballot+popcll -- identical counts, shorter chain than
//     the 7-op shuffle tree; (b) bias is monotone increasing in (a-bb), so
//     bmax = f(max(a-bb)): one sigmoid after the max tree instead of 64 before.
__global__ __launch_bounds__(256) void bmaxthr_kernel(const float* __restrict__ sds,
                                                      const float* __restrict__ U,
                                                      float* __restrict__ thrG,
                                                      float* __restrict__ bmax16) {
  const int h = blockIdx.y, rt = blockIdx.x;
  const int tid = threadIdx.x, ww = tid >> 6, lane = tid & 63;
  __shared__ float thrS[2];
  if (ww < 2) {
    const int row = h * DS + rt * 2 + ww;
    unsigned v[8];
    for (int t = 0; t < 8; ++t) {
      float f = sds[(size_t)row * DS + t * 64 + lane];
      unsigned b = __float_as_uint(f);
      v[t] = (b & 0x80000000u) ? ~b : (b | 0x80000000u);
    }
    unsigned prefix = 0u;
    for (int bit = 31; bit >= 0; --bit) {
      unsigned cand = prefix | (1u << bit);
      int c = 0;
#pragma unroll
      for (int t = 0; t < 8; ++t)
        c += __popcll(__ballot(v[t] >= cand));
      if (c >= 128) prefix = cand;
    }
    if (lane == 0) {
      unsigned b = (prefix & 0x80000000u) ? (prefix ^ 0x80000000u) : ~prefix;
      float t = __uint_as_float(b);
      thrS[ww] = t;
      thrG[row] = t;
    }
  }
  __syncthreads();
  const int r = lane >> 2, q = lane & 3;
  const int i = rt * 16 + r;
  float u = U[i];
  u = fminf(fmaxf(u, 0.0f), 1.0f);
  const float us = 1.0f + u;
  const int idl = r >> 3;
  const float bb = us * thrS[idl];
  const float* srow = &sds[((h * DS) + rt * 2 + idl) * DS];
  for (int c = ww; c < NCH; c += 4) {
    float sval = srow[(c << 2) + q];
    float x = us * sval - bb;  // bias is monotone increasing in x
    for (int off = 1; off < 64; off <<= 1)
      x = fmaxf(x, __shfl_xor(x, off, 64));
    if (lane == 0)
      bmax16[((h * NRT) + rt) * NCH + c] = (1.0f - sigmoidf_(x * 10.0f)) * NEG9;
  }
}

// ---------------- Kernel C: v7 exact revert (swapped-QK^T, register P) ----------------
__global__ __launch_bounds__(512) void attn128_kernel(
    const float* __restrict__ Qf, const _Float16* __restrict__ KVb,
    const float* __restrict__ U, const float* __restrict__ sds,
    const float* __restrict__ thrG, const float* __restrict__ bmax16,
    float* __restrict__ Pm, float* __restrict__ Pl, _Float16* __restrict__ Po,
    const float* __restrict__ Vpart, float* __restrict__ out) {
  const int h = blockIdx.y;
  const int p = TOTSEG2 - 1 - (int)blockIdx.x;  // heavy segs first
  int s = 0;
#pragma unroll
  for (int t = 1; t <= 7; ++t)
    if (p >= 32 * t - 2 * t * (t - 1)) s = t;
  const int g = 4 * s + (p - (32 * s - 2 * s * (s - 1)));
  const int seg = s;
  const int cmax = 4 * g + 4;
  const int c0 = seg * SEG;
  const int len = min(SEG, cmax - c0);
  const int nsegG = (cmax + 15) >> 4;

  const int tid = threadIdx.x;
  const int w = tid >> 6;         // 0..7
  const int lane = tid & 63;
  const int quad = lane >> 4;
  const int n = lane & 15;

  const int rt = g * 8 + w;
  const int iw0 = g * 128 + w * 16;
  const int nchW = (rt >> 1) + 1;

  __shared__ __align__(16) _Float16 Sbuf[2][12288];
  __shared__ unsigned uHot[8], uNN[8];
  __shared__ float VsS[128];

  // per-lane row constants (row i = iw0+n)
  const int myidn = (iw0 >> 3) + (n >> 3);
  float usn, bbn;
  {
    float u = U[iw0 + n];
    u = fminf(fmaxf(u, 0.0f), 1.0f);
    usn = 1.0f + u;
    bbn = usn * thrG[h * DS + myidn];
  }

  // Q fragments (used as MFMA B operand): row i=iw0+n, d-slices
  half8 qfh[4], qfe[4];
  {
    const float* qrow = &Qf[(size_t)((h * T_SEQ) + iw0 + n) * HD + quad * 8];
#pragma unroll
    for (int d = 0; d < 4; ++d) {
      float4 x0 = *(const float4*)&qrow[d * 32];
      float4 x1 = *(const float4*)&qrow[d * 32 + 4];
      float v[8] = {x0.x, x0.y, x0.z, x0.w, x1.x, x1.y, x1.z, x1.w};
      half8 hh, ee;
#pragma unroll
      for (int t = 0; t < 8; ++t) {
        _Float16 hv = (_Float16)v[t];
        hh[t] = hv;
        ee[t] = (_Float16)(v[t] - (float)hv);
      }
      qfh[d] = hh;
      qfe[d] = ee;
    }
  }
  half8 vones;
#pragma unroll
  for (int e = 0; e < 8; ++e) vones[e] = (_Float16)1.0f;

  floatx4 acc[8];
  for (int t = 0; t < 8; ++t) acc[t] = (floatx4){0.f, 0.f, 0.f, 0.f};
  floatx4 accL = (floatx4){0.f, 0.f, 0.f, 0.f};  // l for rows quad*4+r
  float m_ = -INFINITY;                           // stabilizer for row iw0+n

  float bval = -3.0e38f;
  bool validc = false;
  if (lane < len) {
    int c = c0 + lane;
    validc = (c < nchW);
    bval = bmax16[((h * NRT) + rt) * NCH + c];
  }
  const unsigned bits = (1u << len) - 1u;
  const unsigned myHot = (unsigned)__ballot(lane < len && validc && bval > -124.0f) & bits;
  const unsigned myNull = (unsigned)__ballot(lane < len && (!validc || bval == NEG9)) & bits;
  const unsigned myCold = bits & ~myHot & ~myNull;
  if (lane == 0) { uHot[w] = myHot; uNN[w] = myHot | myCold; }
  __syncthreads();
  unsigned it0 = uHot[0] | uHot[1] | uHot[2] | uHot[3] |
                 uHot[4] | uHot[5] | uHot[6] | uHot[7];
  unsigned it1 = (uNN[0] | uNN[1] | uNN[2] | uNN[3] |
                  uNN[4] | uNN[5] | uNN[6] | uNN[7]) & ~it0;

  const size_t hcbase = (size_t)(h * NCH);
#define STAGE(cc, bsel)                                                          \
  {                                                                              \
    const _Float16* gsrc =                                                       \
        KVb + (hcbase + (size_t)(c0 + (cc))) * 12288 + w * 1536 + lane * 8;      \
    _Float16* ldst = &Sbuf[bsel][w * 1536];                                      \
    GLDS16(gsrc, ldst);                                                          \
    GLDS16(gsrc + 512, ldst + 512);                                              \
    GLDS16(gsrc + 1024, ldst + 1024);                                            \
  }

  int curc = -1;
  if (it0) { curc = __builtin_ctz(it0); it0 &= it0 - 1; }
  else if (it1) { curc = __builtin_ctz(it1); it1 &= it1 - 1; }
  int cur = 0;
  if (curc >= 0) STAGE(curc, 0);

  while (curc >= 0) {
    __syncthreads();
    int nxtc = -1;
    if (it0) { nxtc = __builtin_ctz(it0); it0 &= it0 - 1; }
    else if (it1) { nxtc = __builtin_ctz(it1); it1 &= it1 - 1; }
    if (nxtc >= 0) STAGE(nxtc, cur ^ 1);

    bool run = ((myHot | myCold) >> curc) & 1;
    if (run && ((myCold >> curc) & 1)) {
      float bm16 = __shfl(bval, curc, 64);
      float mm = m_;
      for (int d = 1; d < 16; d <<= 1) mm = fminf(mm, __shfl_xor(mm, d, 64));
      if (bm16 + 12.0f < mm - 40.0f) run = false;
    }
    if (run) {
      const _Float16* Sb = &Sbuf[cur][0];
      const int c = c0 + curc;
      const int j0 = c * BN;

      // per-lane bias: 2 sds scalars, 2 sigmoids (no cross-lane traffic)
      const int jj = quad >> 1;
      const float sv1 = sds[((h * DS) + myidn) * DS + (c << 2) + jj];
      const float sv2 = sds[((h * DS) + myidn) * DS + (c << 2) + 2 + jj];
      const float bias1 = (1.0f - sigmoidf_((usn * sv1 - bbn) * 10.0f)) * NEG9;
      const float bias2 = (1.0f - sigmoidf_((usn * sv2 - bbn) * 10.0f)) * NEG9;

      half8 kh0[4], kh1[4];
#pragma unroll
      for (int d = 0; d < 4; ++d) {
        kh0[d] = *(const half8*)&Sb[(size_t)(d * 64 + lane) * 8];
        kh1[d] = *(const half8*)&Sb[(size_t)((4 + d) * 64 + lane) * 8];
      }

      // S^T = K @ Q^T : swapped operands; D row = j (quad*4+r), col = i (n)
      floatx4 S0a = (floatx4){0.f, 0.f, 0.f, 0.f};
      floatx4 S0b = (floatx4){0.f, 0.f, 0.f, 0.f};
      floatx4 S1a = (floatx4){0.f, 0.f, 0.f, 0.f};
      floatx4 S1b = (floatx4){0.f, 0.f, 0.f, 0.f};
      S0a = __builtin_amdgcn_mfma_f32_16x16x32_f16(kh0[0], qfh[0], S0a, 0, 0, 0);
      S0b = __builtin_amdgcn_mfma_f32_16x16x32_f16(kh0[2], qfh[2], S0b, 0, 0, 0);
      S1a = __builtin_amdgcn_mfma_f32_16x16x32_f16(kh1[0], qfh[0], S1a, 0, 0, 0);
      S1b = __builtin_amdgcn_mfma_f32_16x16x32_f16(kh1[2], qfh[2], S1b, 0, 0, 0);
      S0a = __builtin_amdgcn_mfma_f32_16x16x32_f16(kh0[1], qfh[1], S0a, 0, 0, 0);
      S0b = __builtin_amdgcn_mfma_f32_16x16x32_f16(kh0[3], qfh[3], S0b, 0, 0, 0);
      S1a = __builtin_amdgcn_mfma_f32_16x16x32_f16(kh1[1], qfh[1], S1a, 0, 0, 0);
      S1b = __builtin_amdgcn_mfma_f32_16x16x32_f16(kh1[3], qfh[3], S1b, 0, 0, 0);

      S0a = __builtin_amdgcn_mfma_f32_16x16x32_f16(kh0[0], qfe[0], S0a, 0, 0, 0);
      S0b = __builtin_amdgcn_mfma_f32_16x16x32_f16(kh0[2], qfe[2], S0b, 0, 0, 0);
      S1a = __builtin_amdgcn_mfma_f32_16x16x32_f16(kh1[0], qfe[0], S1a, 0, 0, 0);
      S1b = __builtin_amdgcn_mfma_f32_16x16x32_f16(kh1[2], qfe[2], S1b, 0, 0, 0);
      S0a = __builtin_amdgcn_mfma_f32_16x16x32_f16(kh0[1], qfe[1], S0a, 0, 0, 0);
      S0b = __builtin_amdgcn_mfma_f32_16x16x32_f16(kh0[3], qfe[3], S0b, 0, 0, 0);
      S1a = __builtin_amdgcn_mfma_f32_16x16x32_f16(kh1[1], qfe[1], S1a, 0, 0, 0);
      S1b = __builtin_amdgcn_mfma_f32_16x16x32_f16(kh1[3], qfe[3], S1b, 0, 0, 0);

      half8 ke0[4], ke1[4];
#pragma unroll
      for (int d = 0; d < 4; ++d) {
        ke0[d] = *(const half8*)&Sb[4096 + (size_t)(d * 64 + lane) * 8];
        ke1[d] = *(const half8*)&Sb[4096 + (size_t)((4 + d) * 64 + lane) * 8];
      }
      S0a = __builtin_amdgcn_mfma_f32_16x16x32_f16(ke0[0], qfh[0], S0a, 0, 0, 0);
      S0b = __builtin_amdgcn_mfma_f32_16x16x32_f16(ke0[2], qfh[2], S0b, 0, 0, 0);
      S1a = __builtin_amdgcn_mfma_f32_16x16x32_f16(ke1[0], qfh[0], S1a, 0, 0, 0);
      S1b = __builtin_amdgcn_mfma_f32_16x16x32_f16(ke1[2], qfh[2], S1b, 0, 0, 0);
      S0a = __builtin_amdgcn_mfma_f32_16x16x32_f16(ke0[1], qfh[1], S0a, 0, 0, 0);
      S0b = __builtin_amdgcn_mfma_f32_16x16x32_f16(ke0[3], qfh[3], S0b, 0, 0, 0);
      S1a = __builtin_amdgcn_mfma_f32_16x16x32_f16(ke1[1], qfh[1], S1a, 0, 0, 0);
      S1b = __builtin_amdgcn_mfma_f32_16x16x32_f16(ke1[3], qfh[3], S1b, 0, 0, 0);

      const floatx4 S0 = S0a + S0b;  // S[i=n][j = j0 + quad*4+r]
      const floatx4 S1 = S1a + S1b;  // S[i=n][j = j0+16 + quad*4+r]

      const int i = iw0 + n;
      float sc0[4], sc1[4];
      for (int r = 0; r < 4; ++r) {
        const int jA = j0 + quad * 4 + r;
        sc0[r] = (jA <= i) ? (S0[r] * SCALE + bias1) : NEG9;
        sc1[r] = (jA + 16 <= i) ? (S1[r] * SCALE + bias2) : NEG9;
      }

      // T13 defer-max (single m_); tree path: 2-shfl row reduce + alpha gather
      bool within = true;
      for (int r = 0; r < 4; ++r)
        within = within && (sc0[r] <= m_ + 8.0f) && (sc1[r] <= m_ + 8.0f);
      _Float16 ph0[4], ph1[4];
      if (__all(within)) {
        for (int r = 0; r < 4; ++r) {
          ph0[r] = (_Float16)__expf(sc0[r] - m_);
          ph1[r] = (_Float16)__expf(sc1[r] - m_);
        }
      } else {
        float mx = sc0[0];
        for (int r = 1; r < 4; ++r) mx = fmaxf(mx, sc0[r]);
        for (int r = 0; r < 4; ++r) mx = fmaxf(mx, sc1[r]);
        mx = fmaxf(mx, __shfl_xor(mx, 16, 64));
        mx = fmaxf(mx, __shfl_xor(mx, 32, 64));
        const float mnew = fmaxf(m_, mx);
        const float alpha = __expf(m_ - mnew);  // -inf -> 0
        for (int r = 0; r < 4; ++r) {
          ph0[r] = (_Float16)__expf(sc0[r] - mnew);
          ph1[r] = (_Float16)__expf(sc1[r] - mnew);
        }
        m_ = mnew;
        if (__any(alpha != 1.0f)) {
          float aO[4];
#pragma unroll
          for (int r = 0; r < 4; ++r) aO[r] = __shfl(alpha, quad * 4 + r, 64);
          for (int t = 0; t < 8; ++t)
            for (int r = 0; r < 4; ++r) acc[t][r] *= aO[r];
          for (int r = 0; r < 4; ++r) accL[r] *= aO[r];
        }
      }

      // pack P row i=n: k-order matches permuted V blob
      half8 pp;
#pragma unroll
      for (int r = 0; r < 4; ++r) { pp[r] = ph0[r]; pp[4 + r] = ph1[r]; }

      half8 vf[8];
#pragma unroll
      for (int t = 0; t < 8; ++t)
        vf[t] = *(const half8*)&Sb[8192 + (size_t)(t * 64 + lane) * 8];

#pragma unroll
      for (int t = 0; t < 8; ++t)
        acc[t] = __builtin_amdgcn_mfma_f32_16x16x32_f16(pp, vf[t], acc[t], 0, 0, 0);
      accL = __builtin_amdgcn_mfma_f32_16x16x32_f16(pp, vones, accL, 0, 0, 0);
    }
    cur ^= 1;
    curc = nxtc;
  }

  // gather per-output-row m (rows quad*4+r); l is already per-row in accL
  float mrow[4];
#pragma unroll
  for (int r = 0; r < 4; ++r) mrow[r] = __shfl(m_, quad * 4 + r, 64);

  if (nsegG == 1) {
    if (tid < 128) {
      float ss = 0.f;
      for (int pt = 0; pt < NVP; ++pt) ss += Vpart[(h * NVP + pt) * 128 + tid];
      VsS[tid] = ss;
    }
    __syncthreads();
    for (int r = 0; r < 4; ++r) {
      const int row = iw0 + quad * 4 + r;
      const bool dead = (mrow[r] < ALIVE_MIN);
      const float Linv = dead ? 0.0f : 1.0f / accL[r];
#pragma unroll
      for (int t = 0; t < 8; ++t) {
        const int col = t * 16 + n;
        float o = dead ? VsS[col] * 0.000244140625f : acc[t][r] * Linv;
        out[(size_t)((h * T_SEQ) + row) * HD + col] = o;
      }
    }
    return;
  }
  __syncthreads();
  const size_t pbase = (size_t)(h * TOTSEG2 + p);
  if (quad == 0) Pm[pbase * 128 + w * 16 + n] = m_;
  if (n == 0) {
    for (int r = 0; r < 4; ++r)
      Pl[pbase * 128 + w * 16 + quad * 4 + r] = accL[r];
  }
  _Float16* Ob = &Sbuf[0][0];
#pragma unroll
  for (int t = 0; t < 8; ++t)
    for (int r = 0; r < 4; ++r)
      Ob[(size_t)(w * 16 + quad * 4 + r) * 128 + t * 16 + n] = (_Float16)acc[t][r];
  __syncthreads();
  {
    const half8* Os = (const half8*)Ob;
    half8* Pod = (half8*)&Po[pbase * 16384];
    for (int idx = tid; idx < 2048; idx += 512) Pod[idx] = Os[idx];
  }
}

// ---------------- Reduce v2: 16-row sub-blocks, vectorized half8 loads (unchanged) ----------------
__global__ __launch_bounds__(256) void reduce128_kernel(const float* __restrict__ Pm,
                                                        const float* __restrict__ Pl,
                                                        const _Float16* __restrict__ Po,
                                                        const float* __restrict__ Vpart,
                                                        float* __restrict__ out) {
  const int bx = blockIdx.x;
  const int g = 4 + (bx >> 3);        // groups 4..31
  const int rb = bx & 7;              // 16-row sub-block
  const int h = blockIdx.y;
  const int ns = (g >> 2) + 1;        // 2..8
  const int tid = threadIdx.x;
  const int lr = tid >> 4;            // 0..15 local row
  const int d0 = (tid & 15) * 8;      // col start
  const int r = rb * 16 + lr;         // row within 128-row group

  float m[8], M = -INFINITY;
  int pp[8];
#pragma unroll
  for (int ss = 0; ss < 8; ++ss) {
    if (ss < ns) {
      pp[ss] = 32 * ss - 2 * ss * (ss - 1) + g - 4 * ss;
      m[ss] = Pm[(size_t)(h * TOTSEG2 + pp[ss]) * 128 + r];
      M = fmaxf(M, m[ss]);
    }
  }
  const bool dead = (M < ALIVE_MIN);
  float es[8], L = 0.f;
#pragma unroll
  for (int ss = 0; ss < 8; ++ss) {
    if (ss < ns) {
      es[ss] = (dead || m[ss] == -INFINITY) ? 0.0f : expf(m[ss] - M);
      L += Pl[(size_t)(h * TOTSEG2 + pp[ss]) * 128 + r] * es[ss];
    }
  }

  float o[8];
#pragma unroll
  for (int e = 0; e < 8; ++e) o[e] = 0.f;
  if (dead) {
    float4 sa = {0.f, 0.f, 0.f, 0.f}, sb = {0.f, 0.f, 0.f, 0.f};
    for (int pt = 0; pt < NVP; ++pt) {
      const float* vp = &Vpart[(h * NVP + pt) * 128 + d0];
      float4 x0 = *(const float4*)vp;
      float4 x1 = *(const float4*)(vp + 4);
      sa.x += x0.x; sa.y += x0.y; sa.z += x0.z; sa.w += x0.w;
      sb.x += x1.x; sb.y += x1.y; sb.z += x1.z; sb.w += x1.w;
    }
    o[0] = sa.x * 0.000244140625f; o[1] = sa.y * 0.000244140625f;
    o[2] = sa.z * 0.000244140625f; o[3] = sa.w * 0.000244140625f;
    o[4] = sb.x * 0.000244140625f; o[5] = sb.y * 0.000244140625f;
    o[6] = sb.z * 0.000244140625f; o[7] = sb.w * 0.000244140625f;
  } else {
    const float Linv = 1.0f / L;
#pragma unroll
    for (int ss = 0; ss < 8; ++ss) {
      if (ss < ns) {
        half8 v = *(const half8*)&Po[(size_t)(h * TOTSEG2 + pp[ss]) * 16384 + r * 128 + d0];
#pragma unroll
        for (int e = 0; e < 8; ++e) o[e] += (float)v[e] * es[ss];
      }
    }
#pragma unroll
    for (int e = 0; e < 8; ++e) o[e] *= Linv;
  }
  float* dst = &out[(size_t)((h * T_SEQ) + g * 128 + r) * HD + d0];
  float4 w0 = {o[0], o[1], o[2], o[3]};
  float4 w1 = {o[4], o[5], o[6], o[7]};
  *(float4*)dst = w0;
  *(float4*)(dst + 4) = w1;
}

extern "C" void kernel_launch(void* const* d_in, const int* in_sizes, int n_in,
                              void* d_out, int out_size, void* d_ws, size_t ws_size,
                              hipStream_t stream) {
  const float* Q = (const float*)d_in[0];
  const float* K = (const float*)d_in[1];
  const float* V = (const float*)d_in[2];
  const float* U = (const float*)d_in[3];
  float* out = (float*)d_out;

  char* wsb = (char*)d_ws;
  float* sds = (float*)wsb;                        // 4 MB
  float* thrG = (float*)(wsb + 4194304);           // 8 KB
  float* bmax16 = (float*)(wsb + 4202496);         // 512 KB
  float* Vpart = (float*)(wsb + 4726784);          // 64 KB
  _Float16* KVb = (_Float16*)(wsb + 4792320);      // 12 MB chunk blobs (Kh|Ke|V)
  float* Pm = (float*)(wsb + 17375232);            // 288 KB
  float* Pl = (float*)(wsb + 17670144);            // 288 KB
  _Float16* Po = (_Float16*)(wsb + 17965056);      // 18.9 MB -> total ~35.2 MB

  prepsds_kernel<<<4736, 256, 0, stream>>>(Q, K, V, KVb, Vpart, sds);
  bmaxthr_kernel<<<dim3(NRT, NH), 256, 0, stream>>>(sds, U, thrG, bmax16);
  attn128_kernel<<<dim3(TOTSEG2, NH), 512, 0, stream>>>(Q, KVb, U, sds, thrG, bmax16,
                                                        Pm, Pl, Po, Vpart, out);
  reduce128_kernel<<<dim3(224, NH), 256, 0, stream>>>(Pm, Pl, Po, Vpart, out);
}